// Round 6
// baseline (398.547 us; speedup 1.0000x reference)
//
#include <hip/hip_runtime.h>
#include <hip/hip_cooperative_groups.h>
#include <math.h>

namespace cg = cooperative_groups;

#define F_IN 128
#define C 64
#define ELCAP 128
#define E2CAP 4096
#define E1CAP 32768
#define S0CAP 49152
#define S1CAP 4096
#define NBLK 256
#define NTHR 256
#define GSZ (NBLK * NTHR)
#define EBCAP 3200   // >= ceil(nE/NBLK) = 3125 per-block worst case

#define I_EL 0
#define I_E2 1
#define I_E1 2
#define I_S0 3
#define I_S1 4

struct Params {
  const float* x; const int* src; const int* dst; const int* node_p;
  const float* w1; const float* b1; const float* w2; const float* b2;
  const float* w_ro; const float* b_ro;
  int* deg; int* tflag; int* mark0; int* mark1; int* map0; int* map1;
  int* elist; int* s0list; int* s1list;
  int* e2s; int* e2d; int* e1s; int* e1d; int* cnt;
  float* agg1c; float* xw1c; float* xw2c;
  float* out;
  int nE, nN, K;
};

__device__ __forceinline__ void mark_append(int n, int* mark, int* map, int* list,
                                            int* cntp, int cap) {
  if (atomicCAS(&mark[n], 0, 1) == 0) {
    int idx = atomicAdd(cntp, 1);
    if (idx < cap) { list[idx] = n; map[n] = idx; }
  }
}

__global__ __launch_bounds__(NTHR, 1) void fused_kernel(Params p) {
  cg::grid_group grid = cg::this_grid();
  __shared__ __align__(16) char smemRaw[49152];   // phase-shared union (48 KB)
  __shared__ int cA, cB, bA, bB;
  const int t = threadIdx.x, bid = blockIdx.x;
  const int gtid = bid * NTHR + t;
  const int node = *p.node_p;

  // ---- P0: zero working arrays ----
  for (int i = gtid; i < p.nN; i += GSZ) {
    p.deg[i] = 0; p.tflag[i] = 0; p.mark0[i] = 0; p.mark1[i] = 0;
  }
  if (gtid < 16) p.cnt[gtid] = 0;
  grid.sync();

  // ---- P1: one full edge pass: deg histogram + masked edges + T appends ----
  for (int e = gtid; e < p.nE; e += GSZ) {
    int s = p.src[e], d = p.dst[e];
    atomicAdd(&p.deg[d], 1);
    if (s == node || d == node) {
      int q = atomicAdd(&p.cnt[I_EL], 1);
      if (q < ELCAP) p.elist[q] = e;
      int tgt = (s == node) ? d : s;
      p.tflag[tgt] = 1;   // scanB membership test (frozen set T)
      mark_append(tgt, p.mark1, p.map1, p.s1list, &p.cnt[I_S1], S1CAP);
      mark_append(tgt, p.mark0, p.map0, p.s0list, &p.cnt[I_S0], S0CAP);
    }
  }
  grid.sync();

  // ---- P2: scanB — edges with dst in T -> e2; new srcs -> S1 (LDS-aggregated) ----
  {
    int* ebS = (int*)smemRaw; int* ebD = ebS + EBCAP; int* nb = ebD + EBCAP;
    if (t == 0) { cA = 0; cB = 0; }
    __syncthreads();
    int chunk = (p.nE + NBLK - 1) / NBLK;
    int e0 = bid * chunk, e1 = min(e0 + chunk, p.nE);
    for (int e = e0 + t; e < e1; e += NTHR) {
      int d = p.dst[e];
      if (p.tflag[d]) {
        int s = p.src[e];
        int q = atomicAdd(&cA, 1); if (q < EBCAP) { ebS[q] = s; ebD[q] = d; }
        if (atomicCAS(&p.mark1[s], 0, 1) == 0) { int w = atomicAdd(&cB, 1); nb[w] = s; }
      }
    }
    __syncthreads();
    if (t == 0) {
      bA = atomicAdd(&p.cnt[I_E2], min(cA, EBCAP));
      bB = atomicAdd(&p.cnt[I_S1], cB);
    }
    __syncthreads();
    int nA = min(cA, EBCAP);
    for (int i = t; i < nA; i += NTHR) {
      int q = bA + i; if (q < E2CAP) { p.e2s[q] = ebS[i]; p.e2d[q] = ebD[i]; }
    }
    for (int i = t; i < cB; i += NTHR) {
      int q = bB + i; if (q < S1CAP) { p.s1list[q] = nb[i]; p.map1[nb[i]] = q; }
    }
  }
  grid.sync();

  // ---- P3: S1 -> S0 prologue + scanC — edges with dst in S1 -> e1; new srcs -> S0 ----
  {
    int* ebS = (int*)smemRaw; int* ebD = ebS + EBCAP; int* nb = ebD + EBCAP;
    if (t == 0) { cA = 0; cB = 0; }
    __syncthreads();
    int s1c = min(p.cnt[I_S1], S1CAP);
    for (int i = gtid; i < s1c; i += GSZ)
      mark_append(p.s1list[i], p.mark0, p.map0, p.s0list, &p.cnt[I_S0], S0CAP);
    int chunk = (p.nE + NBLK - 1) / NBLK;
    int e0 = bid * chunk, e1 = min(e0 + chunk, p.nE);
    for (int e = e0 + t; e < e1; e += NTHR) {
      int d = p.dst[e];
      if (p.mark1[d]) {
        int s = p.src[e];
        int q = atomicAdd(&cA, 1); if (q < EBCAP) { ebS[q] = s; ebD[q] = d; }
        if (atomicCAS(&p.mark0[s], 0, 1) == 0) { int w = atomicAdd(&cB, 1); nb[w] = s; }
      }
    }
    __syncthreads();
    if (t == 0) {
      bA = atomicAdd(&p.cnt[I_E1], min(cA, EBCAP));
      bB = atomicAdd(&p.cnt[I_S0], cB);
    }
    __syncthreads();
    int nA = min(cA, EBCAP);
    for (int i = t; i < nA; i += NTHR) {
      int q = bA + i; if (q < E1CAP) { p.e1s[q] = ebS[i]; p.e1d[q] = ebD[i]; }
    }
    for (int i = t; i < cB; i += NTHR) {
      int q = bB + i; if (q < S0CAP) { p.s0list[q] = nb[i]; p.map0[nb[i]] = q; }
    }
  }
  grid.sync();

  // ---- P4: zero agg1c rows + xw1c = x[s0list] @ w1 ----
  {
    int s1c = min(p.cnt[I_S1], S1CAP);
    for (int i = gtid; i < s1c * C; i += GSZ) p.agg1c[i] = 0.0f;
    int s0c = min(p.cnt[I_S0], S0CAP);
    float* ws = (float*)smemRaw;      // 8192 floats
    float* xs = ws + F_IN * C;        // 4096 floats
    for (int i = t; i < F_IN * C; i += NTHR) ws[i] = p.w1[i];
    int ntile = (s0c + 31) / 32;
    for (int tile = bid; tile < ntile; tile += NBLK) {
      __syncthreads();
      int r0 = tile * 32;
      for (int i = t; i < 32 * F_IN; i += NTHR) {
        int r = r0 + (i >> 7);
        xs[i] = (r < s0c) ? p.x[(size_t)p.s0list[r] * F_IN + (i & 127)] : 0.0f;
      }
      __syncthreads();
      int c = t & 63, rb = t >> 6;
      float acc[8];
#pragma unroll
      for (int j = 0; j < 8; ++j) acc[j] = 0.f;
      for (int k = 0; k < F_IN; ++k) {
        float wv = ws[k * C + c];
#pragma unroll
        for (int j = 0; j < 8; ++j)
          acc[j] += xs[(rb + j * 4) * F_IN + k] * wv;
      }
#pragma unroll
      for (int j = 0; j < 8; ++j) {
        int r = r0 + rb + j * 4;
        if (r < s0c) p.xw1c[(size_t)r * C + c] = acc[j];
      }
    }
  }
  grid.sync();

  // ---- P5: gather1 — accumulate E1 into agg1c (wave per edge, lane = channel) ----
  {
    int n1 = min(p.cnt[I_E1], E1CAP);
    int s0c = min(p.cnt[I_S0], S0CAP);
    long total = (long)n1 * 64;
    for (long i = (long)gtid; i < total; i += GSZ) {
      int e = (int)(i >> 6), c = (int)(i & 63);
      int s = p.e1s[e], d = p.e1d[e];
      int ms = p.map0[s];
      if ((unsigned)ms < (unsigned)s0c) {
        float w = rsqrtf((float)p.deg[s] + 1.0f) * rsqrtf((float)p.deg[d] + 1.0f);
        atomicAdd(&p.agg1c[(size_t)p.map1[d] * C + c], w * p.xw1c[(size_t)ms * C + c]);
      }
    }
  }
  grid.sync();

  // ---- P6: xw2c = relu(agg1c + self + b1) @ w2 ----
  {
    int sc = min(p.cnt[I_S1], S1CAP);
    float* ws = (float*)smemRaw;      // 4096 floats
    float* xs = ws + C * C;           // 4096 floats
    for (int i = t; i < C * C; i += NTHR) ws[i] = p.w2[i];
    int ntile = (sc + 63) / 64;
    for (int tile = bid; tile < ntile; tile += NBLK) {
      __syncthreads();
      int r0 = tile * 64;
      for (int i = t; i < 64 * C; i += NTHR) {
        int r = r0 + (i >> 6), cc = i & 63;
        float v = 0.0f;
        if (r < sc) {
          int nd = p.s1list[r];
          float dv = rsqrtf((float)p.deg[nd] + 1.0f);
          v = fmaxf(p.agg1c[(size_t)r * C + cc] +
                    p.xw1c[(size_t)p.map0[nd] * C + cc] * dv * dv + p.b1[cc], 0.0f);
        }
        xs[i] = v;
      }
      __syncthreads();
      int c = t & 63, rb = t >> 6;
      float acc[16];
#pragma unroll
      for (int j = 0; j < 16; ++j) acc[j] = 0.f;
      for (int k = 0; k < C; ++k) {
        float wv = ws[k * C + c];
#pragma unroll
        for (int j = 0; j < 16; ++j)
          acc[j] += xs[(rb + j * 4) * C + k] * wv;
      }
#pragma unroll
      for (int j = 0; j < 16; ++j) {
        int r = r0 + rb + j * 4;
        if (r < sc) p.xw2c[(size_t)r * C + c] = acc[j];
      }
    }
  }
  grid.sync();

  // ---- P7: readout (block 0 only): gather2 into LDS + rank-ordered sigmoid ----
  if (bid == 0) {
    float* aggL = (float*)smemRaw;            // ELCAP*C = 8192 floats (32 KB)
    int* ids = (int*)(aggL + ELCAP * C);      // 128 ints
    int n = p.cnt[I_EL];
    if (n > p.K) n = p.K;
    if (n > ELCAP) n = ELCAP;
    for (int i = t; i < ELCAP * C; i += NTHR) aggL[i] = 0.0f;
    for (int i = t; i < n; i += NTHR) ids[i] = p.elist[i];
    __syncthreads();
    int n2 = min(p.cnt[I_E2], E2CAP);
    int wid = t >> 6, lane = t & 63;
    for (int i = wid; i < n2; i += (NTHR / 64)) {
      int s = p.e2s[i], d = p.e2d[i];
      int q = p.map1[d];
      if (q < ELCAP) {
        float w = rsqrtf((float)p.deg[s] + 1.0f) * rsqrtf((float)p.deg[d] + 1.0f);
        atomicAdd(&aggL[q * C + lane], w * p.xw2c[(size_t)p.map1[s] * C + lane]);
      }
    }
    __syncthreads();
    for (int i = t; i < n; i += NTHR) {
      int eid = ids[i];
      int rank = 0;
      for (int j = 0; j < n; ++j) rank += (ids[j] < eid) ? 1 : 0;
      int s = p.src[eid], d = p.dst[eid];
      int tgt = (s == node) ? d : s;
      int q = p.map1[tgt];
      float dv = rsqrtf((float)p.deg[tgt] + 1.0f);
      float acc = 0.f;
      for (int c2 = 0; c2 < C; ++c2) {
        float h = aggL[q * C + c2] + p.xw2c[(size_t)q * C + c2] * dv * dv + p.b2[c2];
        acc += fmaxf(h, 0.f) * p.w_ro[c2];
      }
      acc += p.b_ro[0];
      p.out[rank] = 1.0f / (1.0f + expf(-acc));
      p.out[p.K + rank] = (float)tgt;
    }
  }
}

extern "C" void kernel_launch(void* const* d_in, const int* in_sizes, int n_in,
                              void* d_out, int out_size, void* d_ws, size_t ws_size,
                              hipStream_t stream) {
  Params p;
  p.x    = (const float*)d_in[0];
  const int* ei = (const int*)d_in[1];
  p.node_p = (const int*)d_in[3];
  p.w1   = (const float*)d_in[5];
  p.b1   = (const float*)d_in[6];
  p.w2   = (const float*)d_in[7];
  p.b2   = (const float*)d_in[8];
  p.w_ro = (const float*)d_in[9];
  p.b_ro = (const float*)d_in[10];
  p.out  = (float*)d_out;

  p.nE = in_sizes[1] / 2;
  p.nN = in_sizes[0] / F_IN;
  p.src = ei;
  p.dst = ei + p.nE;
  p.K = out_size / 2;

  // ws layout (4-byte units)
  int* w = (int*)d_ws;
  p.deg    = w;               w += p.nN;
  p.tflag  = w;               w += p.nN;
  p.mark0  = w;               w += p.nN;
  p.mark1  = w;               w += p.nN;
  p.map0   = w;               w += p.nN;
  p.map1   = w;               w += p.nN;
  p.elist  = w;               w += ELCAP;
  p.s0list = w;               w += S0CAP;
  p.s1list = w;               w += S1CAP;
  p.e2s    = w;               w += E2CAP;
  p.e2d    = w;               w += E2CAP;
  p.e1s    = w;               w += E1CAP;
  p.e1d    = w;               w += E1CAP;
  p.cnt    = w;               w += 16;
  p.agg1c  = (float*)w;       w += S1CAP * C;
  p.xw1c   = (float*)w;       w += (size_t)S0CAP * C;
  p.xw2c   = (float*)w;       w += S1CAP * C;

  void* args[] = { (void*)&p };
  hipLaunchCooperativeKernel((const void*)fused_kernel, dim3(NBLK), dim3(NTHR),
                             args, 0, stream);
}

// Round 7
// 215.661 us; speedup vs baseline: 1.8480x; 1.8480x over previous
//
#include <hip/hip_runtime.h>
#include <math.h>

#define F_IN 128
#define C 64
#define ELCAP 128
#define E2CAP 4096
#define E1CAP 32768
#define S1CAP 4096
#define NSCAN 512          // blocks for segmented scans
#define EBCAP 1600         // >= ceil(nE/NSCAN) = 1563

#define I_EL 0
#define I_E2 1
#define I_E1 2
#define I_S1 3

// K1: ONE full edge pass — deg histogram + masked-edge detect + T appends (+ self-edges)
__global__ __launch_bounds__(256) void mask_hist_kernel(const int* __restrict__ src,
    const int* __restrict__ dst, const int* __restrict__ node_p,
    int* __restrict__ deg, int* __restrict__ tflag, int* __restrict__ mark1,
    int* __restrict__ map1, int* __restrict__ elist, int* __restrict__ s1list,
    int* __restrict__ e1s, int* __restrict__ e1d, int* __restrict__ cnt, int nE) {
  int e = blockIdx.x * 256 + threadIdx.x;
  if (e >= nE) return;
  int node = *node_p;
  int s = src[e], d = dst[e];
  atomicAdd(&deg[d], 1);
  if (s == node || d == node) {
    int q = atomicAdd(&cnt[I_EL], 1);
    if (q < ELCAP) elist[q] = e;
    int tgt = (s == node) ? d : s;
    tflag[tgt] = 1;
    if (atomicCAS(&mark1[tgt], 0, 1) == 0) {
      int idx = atomicAdd(&cnt[I_S1], 1);
      if (idx < S1CAP) { s1list[idx] = tgt; map1[tgt] = idx; }
      int p = atomicAdd(&cnt[I_E1], 1);
      if (p < E1CAP) { e1s[p] = tgt; e1d[p] = tgt; }   // self-loop pseudo-edge
    }
  }
}

// K2: full pass — dst in T -> e2; new srcs -> S1 (+ self-edges). Block-LDS aggregated.
__global__ __launch_bounds__(256) void scanB_kernel(const int* __restrict__ src,
    const int* __restrict__ dst, const int* __restrict__ tflag,
    int* __restrict__ mark1, int* __restrict__ map1, int* __restrict__ s1list,
    int* __restrict__ e2s, int* __restrict__ e2d, int* __restrict__ e1s,
    int* __restrict__ e1d, int* __restrict__ cnt, int nE) {
  __shared__ int ebS[EBCAP], ebD[EBCAP], nb[EBCAP];
  __shared__ int cA, cB, bA, bB, bC;
  int t = threadIdx.x;
  if (t == 0) { cA = 0; cB = 0; }
  __syncthreads();
  int chunk = (nE + NSCAN - 1) / NSCAN;
  int e0 = blockIdx.x * chunk, e1 = min(e0 + chunk, nE);
  for (int e = e0 + t; e < e1; e += 256) {
    int d = dst[e];
    if (tflag[d]) {
      int s = src[e];
      int q = atomicAdd(&cA, 1);
      ebS[q] = s; ebD[q] = d;
      if (atomicCAS(&mark1[s], 0, 1) == 0) nb[atomicAdd(&cB, 1)] = s;
    }
  }
  __syncthreads();
  if (t == 0) {
    bA = atomicAdd(&cnt[I_E2], cA);
    bB = atomicAdd(&cnt[I_S1], cB);
    bC = atomicAdd(&cnt[I_E1], cB);
  }
  __syncthreads();
  for (int i = t; i < cA; i += 256) {
    int q = bA + i; if (q < E2CAP) { e2s[q] = ebS[i]; e2d[q] = ebD[i]; }
  }
  for (int i = t; i < cB; i += 256) {
    int v = nb[i];
    int q = bB + i; if (q < S1CAP) { s1list[q] = v; map1[v] = q; }
    int p = bC + i; if (p < E1CAP) { e1s[p] = v; e1d[p] = v; }  // self-loop
  }
}

// K3: full pass — dst in S1 -> e1. Block-LDS aggregated. No new marking needed.
__global__ __launch_bounds__(256) void scanC_kernel(const int* __restrict__ src,
    const int* __restrict__ dst, const int* __restrict__ mark1,
    int* __restrict__ e1s, int* __restrict__ e1d, int* __restrict__ cnt, int nE) {
  __shared__ int ebS[EBCAP], ebD[EBCAP];
  __shared__ int cA, bA;
  int t = threadIdx.x;
  if (t == 0) cA = 0;
  __syncthreads();
  int chunk = (nE + NSCAN - 1) / NSCAN;
  int e0 = blockIdx.x * chunk, e1 = min(e0 + chunk, nE);
  for (int e = e0 + t; e < e1; e += 256) {
    int d = dst[e];
    if (mark1[d]) {
      int q = atomicAdd(&cA, 1);
      ebS[q] = src[e]; ebD[q] = d;
    }
  }
  __syncthreads();
  if (t == 0) bA = atomicAdd(&cnt[I_E1], cA);
  __syncthreads();
  for (int i = t; i < cA; i += 256) {
    int q = bA + i; if (q < E1CAP) { e1s[q] = ebS[i]; e1d[q] = ebD[i]; }
  }
}

// K4: per-edge GEMM layer 1 — row e: x[e1s[e]] @ w1 * w_e, atomic-add into agg1c[map1[e1d[e]]]
__global__ __launch_bounds__(256) void edgegemm1_kernel(const float* __restrict__ x,
    const float* __restrict__ w, const int* __restrict__ e1s,
    const int* __restrict__ e1d, const int* __restrict__ deg,
    const int* __restrict__ map1, float* __restrict__ agg1c,
    const int* __restrict__ cnt) {
  __shared__ float ws[F_IN * C];   // 32 KB
  __shared__ float xs[32 * F_IN];  // 16 KB
  __shared__ int qidx[32];
  __shared__ float wgt[32];
  int t = threadIdx.x;
  int n1 = cnt[I_E1]; if (n1 > E1CAP) n1 = E1CAP;
  int s1c = cnt[I_S1]; if (s1c > S1CAP) s1c = S1CAP;
  for (int i = t; i < F_IN * C; i += 256) ws[i] = w[i];
  int ntile = (n1 + 31) / 32;
  for (int tile = blockIdx.x; tile < ntile; tile += gridDim.x) {
    __syncthreads();
    int r0 = tile * 32;
    for (int i = t; i < 32 * F_IN; i += 256) {
      int r = r0 + (i >> 7);
      xs[i] = (r < n1) ? x[(size_t)e1s[r] * F_IN + (i & 127)] : 0.0f;
    }
    if (t < 32) {
      int r = r0 + t;
      if (r < n1) {
        int s = e1s[r], d = e1d[r];
        int q = map1[d];
        qidx[t] = ((unsigned)q < (unsigned)s1c) ? q : -1;
        wgt[t] = rsqrtf((float)deg[s] + 1.0f) * rsqrtf((float)deg[d] + 1.0f);
      } else qidx[t] = -1;
    }
    __syncthreads();
    int c = t & 63, rb = t >> 6;
    float acc[8];
#pragma unroll
    for (int j = 0; j < 8; ++j) acc[j] = 0.f;
    for (int k = 0; k < F_IN; ++k) {
      float wv = ws[k * C + c];
#pragma unroll
      for (int j = 0; j < 8; ++j)
        acc[j] += xs[(rb + j * 4) * F_IN + k] * wv;
    }
#pragma unroll
    for (int j = 0; j < 8; ++j) {
      int r = rb + j * 4;
      int q = qidx[r];
      if (q >= 0) atomicAdd(&agg1c[(size_t)q * C + c], acc[j] * wgt[r]);
    }
  }
}

// K5: xw2c = relu(agg1c + b1) @ w2  (self-term already in agg1c via pseudo-edges)
__global__ __launch_bounds__(256) void gemm2c_kernel(const float* __restrict__ agg1c,
    const float* __restrict__ b1, const float* __restrict__ w,
    float* __restrict__ xw2c, const int* __restrict__ cnt) {
  __shared__ float ws[C * C];   // 16 KB
  __shared__ float xs[64 * C];  // 16 KB
  int t = threadIdx.x;
  int sc = cnt[I_S1]; if (sc > S1CAP) sc = S1CAP;
  for (int i = t; i < C * C; i += 256) ws[i] = w[i];
  int ntile = (sc + 63) / 64;
  for (int tile = blockIdx.x; tile < ntile; tile += gridDim.x) {
    __syncthreads();
    int r0 = tile * 64;
    for (int i = t; i < 64 * C; i += 256) {
      int r = r0 + (i >> 6), cc = i & 63;
      xs[i] = (r < sc) ? fmaxf(agg1c[(size_t)r * C + cc] + b1[cc], 0.0f) : 0.0f;
    }
    __syncthreads();
    int c = t & 63, rb = t >> 6;
    float acc[16];
#pragma unroll
    for (int j = 0; j < 16; ++j) acc[j] = 0.f;
    for (int k = 0; k < C; ++k) {
      float wv = ws[k * C + c];
#pragma unroll
      for (int j = 0; j < 16; ++j)
        acc[j] += xs[(rb + j * 4) * C + k] * wv;
    }
#pragma unroll
    for (int j = 0; j < 16; ++j) {
      int r = r0 + rb + j * 4;
      if (r < sc) xw2c[(size_t)r * C + c] = acc[j];
    }
  }
}

// K6: single block — gather2 (E2) into LDS + layer-2 self-term + rank-ordered sigmoid
__global__ __launch_bounds__(256) void readout_kernel(const int* __restrict__ src,
    const int* __restrict__ dst, const int* __restrict__ e2s,
    const int* __restrict__ e2d, const int* __restrict__ deg,
    const int* __restrict__ map1, const float* __restrict__ xw2c,
    const float* __restrict__ b2, const float* __restrict__ w_ro,
    const float* __restrict__ b_ro, const int* __restrict__ node_p,
    const int* __restrict__ elist, const int* __restrict__ cnt,
    int K, float* __restrict__ out) {
  __shared__ float aggL[ELCAP * C];  // 32 KB
  __shared__ int ids[ELCAP];
  int t = threadIdx.x;
  int n = cnt[I_EL];
  if (n > K) n = K;
  if (n > ELCAP) n = ELCAP;
  for (int i = t; i < ELCAP * C; i += 256) aggL[i] = 0.0f;
  for (int i = t; i < n; i += 256) ids[i] = elist[i];
  __syncthreads();
  int n2 = cnt[I_E2]; if (n2 > E2CAP) n2 = E2CAP;
  int wid = t >> 6, lane = t & 63;
  for (int i = wid; i < n2; i += 4) {
    int s = e2s[i], d = e2d[i];
    int q = map1[d];
    if ((unsigned)q < (unsigned)ELCAP) {
      float w = rsqrtf((float)deg[s] + 1.0f) * rsqrtf((float)deg[d] + 1.0f);
      atomicAdd(&aggL[q * C + lane], w * xw2c[(size_t)map1[s] * C + lane]);
    }
  }
  __syncthreads();
  int node = *node_p;
  for (int i = t; i < n; i += 256) {
    int eid = ids[i];
    int rank = 0;
    for (int j = 0; j < n; ++j) rank += (ids[j] < eid) ? 1 : 0;
    int s = src[eid], d = dst[eid];
    int tgt = (s == node) ? d : s;
    int q = map1[tgt];
    float dv = rsqrtf((float)deg[tgt] + 1.0f);
    float acc = 0.f;
    for (int c2 = 0; c2 < C; ++c2) {
      float h = aggL[q * C + c2] + xw2c[(size_t)q * C + c2] * dv * dv + b2[c2];
      acc += fmaxf(h, 0.f) * w_ro[c2];
    }
    acc += b_ro[0];
    out[rank] = 1.0f / (1.0f + expf(-acc));
    out[K + rank] = (float)tgt;
  }
}

extern "C" void kernel_launch(void* const* d_in, const int* in_sizes, int n_in,
                              void* d_out, int out_size, void* d_ws, size_t ws_size,
                              hipStream_t stream) {
  const float* x    = (const float*)d_in[0];
  const int*   ei   = (const int*)d_in[1];
  const int*   node = (const int*)d_in[3];
  const float* w1   = (const float*)d_in[5];
  const float* b1   = (const float*)d_in[6];
  const float* w2   = (const float*)d_in[7];
  const float* b2   = (const float*)d_in[8];
  const float* w_ro = (const float*)d_in[9];
  const float* b_ro = (const float*)d_in[10];
  float* out = (float*)d_out;

  int nE = in_sizes[1] / 2;
  int nN = in_sizes[0] / F_IN;
  const int* src = ei;
  const int* dst = ei + nE;
  int K = out_size / 2;

  // ws layout (4-byte units); [deg|tflag|mark1|cnt|agg1c] contiguous -> ONE memset
  int* w = (int*)d_ws;
  int*   deg    = w;          w += nN;
  int*   tflag  = w;          w += nN;
  int*   mark1  = w;          w += nN;
  int*   cnt    = w;          w += 16;
  float* agg1c  = (float*)w;  w += (size_t)S1CAP * C;
  int*   map1   = w;          w += nN;
  int*   elist  = w;          w += ELCAP;
  int*   s1list = w;          w += S1CAP;
  int*   e2s    = w;          w += E2CAP;
  int*   e2d    = w;          w += E2CAP;
  int*   e1s    = w;          w += E1CAP;
  int*   e1d    = w;          w += E1CAP;
  float* xw2c   = (float*)w;  w += (size_t)S1CAP * C;

  hipMemsetAsync(deg, 0, ((size_t)3 * nN + 16 + (size_t)S1CAP * C) * 4, stream);

  mask_hist_kernel<<<(nE + 255) / 256, 256, 0, stream>>>(src, dst, node, deg, tflag,
      mark1, map1, elist, s1list, e1s, e1d, cnt, nE);
  scanB_kernel<<<NSCAN, 256, 0, stream>>>(src, dst, tflag, mark1, map1, s1list,
      e2s, e2d, e1s, e1d, cnt, nE);
  scanC_kernel<<<NSCAN, 256, 0, stream>>>(src, dst, mark1, e1s, e1d, cnt, nE);
  edgegemm1_kernel<<<512, 256, 0, stream>>>(x, w1, e1s, e1d, deg, map1, agg1c, cnt);
  gemm2c_kernel<<<16, 256, 0, stream>>>(agg1c, b1, w2, xw2c, cnt);
  readout_kernel<<<1, 256, 0, stream>>>(src, dst, e2s, e2d, deg, map1, xw2c, b2,
                                        w_ro, b_ro, node, elist, cnt, K, out);
}

// Round 8
// 119.756 us; speedup vs baseline: 3.3280x; 1.8008x over previous
//
#include <hip/hip_runtime.h>
#include <math.h>

#define F_IN 128
#define C 64
#define ELCAP 128
#define E2CAP 4096
#define E1CAP 32768
#define S1CAP 4096
#define NSCAN 512          // blocks for segmented scans
#define EBCAP 1600         // >= ceil(nE/NSCAN) = 1563

#define I_EL 0
#define I_E2 1
#define I_E1 2
#define I_S1 3

// K1: ONE full edge pass — deg histogram + masked-edge detect + T appends (+ self-edges)
__global__ __launch_bounds__(256) void mask_hist_kernel(const int* __restrict__ src,
    const int* __restrict__ dst, const int* __restrict__ node_p,
    int* __restrict__ deg, int* __restrict__ tflag, int* __restrict__ mark1,
    int* __restrict__ map1, int* __restrict__ elist, int* __restrict__ s1list,
    int* __restrict__ e1s, int* __restrict__ e1d, int* __restrict__ cnt, int nE) {
  int e = blockIdx.x * 256 + threadIdx.x;
  if (e >= nE) return;
  int node = *node_p;
  int s = src[e], d = dst[e];
  atomicAdd(&deg[d], 1);
  if (s == node || d == node) {
    int q = atomicAdd(&cnt[I_EL], 1);
    if (q < ELCAP) elist[q] = e;
    int tgt = (s == node) ? d : s;
    tflag[tgt] = 1;
    if (atomicCAS(&mark1[tgt], 0, 1) == 0) {
      int idx = atomicAdd(&cnt[I_S1], 1);
      if (idx < S1CAP) { s1list[idx] = tgt; map1[tgt] = idx; }
      int p = atomicAdd(&cnt[I_E1], 1);
      if (p < E1CAP) { e1s[p] = tgt; e1d[p] = tgt; }   // self-loop pseudo-edge
    }
  }
}

// K2: full pass — dst in T -> e2; new srcs -> S1 (+ self-edges). Block-LDS aggregated.
__global__ __launch_bounds__(256) void scanB_kernel(const int* __restrict__ src,
    const int* __restrict__ dst, const int* __restrict__ tflag,
    int* __restrict__ mark1, int* __restrict__ map1, int* __restrict__ s1list,
    int* __restrict__ e2s, int* __restrict__ e2d, int* __restrict__ e1s,
    int* __restrict__ e1d, int* __restrict__ cnt, int nE) {
  __shared__ int ebS[EBCAP], ebD[EBCAP], nb[EBCAP];
  __shared__ int cA, cB, bA, bB, bC;
  int t = threadIdx.x;
  if (t == 0) { cA = 0; cB = 0; }
  __syncthreads();
  int chunk = (nE + NSCAN - 1) / NSCAN;
  int e0 = blockIdx.x * chunk, e1 = min(e0 + chunk, nE);
  for (int e = e0 + t; e < e1; e += 256) {
    int d = dst[e];
    if (tflag[d]) {
      int s = src[e];
      int q = atomicAdd(&cA, 1);
      ebS[q] = s; ebD[q] = d;
      if (atomicCAS(&mark1[s], 0, 1) == 0) nb[atomicAdd(&cB, 1)] = s;
    }
  }
  __syncthreads();
  if (t == 0) {
    bA = atomicAdd(&cnt[I_E2], cA);
    bB = atomicAdd(&cnt[I_S1], cB);
    bC = atomicAdd(&cnt[I_E1], cB);
  }
  __syncthreads();
  for (int i = t; i < cA; i += 256) {
    int q = bA + i; if (q < E2CAP) { e2s[q] = ebS[i]; e2d[q] = ebD[i]; }
  }
  for (int i = t; i < cB; i += 256) {
    int v = nb[i];
    int q = bB + i; if (q < S1CAP) { s1list[q] = v; map1[v] = q; }
    int p = bC + i; if (p < E1CAP) { e1s[p] = v; e1d[p] = v; }  // self-loop
  }
}

// K3: full pass — dst in S1 -> e1. Block-LDS aggregated.
__global__ __launch_bounds__(256) void scanC_kernel(const int* __restrict__ src,
    const int* __restrict__ dst, const int* __restrict__ mark1,
    int* __restrict__ e1s, int* __restrict__ e1d, int* __restrict__ cnt, int nE) {
  __shared__ int ebS[EBCAP], ebD[EBCAP];
  __shared__ int cA, bA;
  int t = threadIdx.x;
  if (t == 0) cA = 0;
  __syncthreads();
  int chunk = (nE + NSCAN - 1) / NSCAN;
  int e0 = blockIdx.x * chunk, e1 = min(e0 + chunk, nE);
  for (int e = e0 + t; e < e1; e += 256) {
    int d = dst[e];
    if (mark1[d]) {
      int q = atomicAdd(&cA, 1);
      ebS[q] = src[e]; ebD[q] = d;
    }
  }
  __syncthreads();
  if (t == 0) bA = atomicAdd(&cnt[I_E1], cA);
  __syncthreads();
  for (int i = t; i < cA; i += 256) {
    int q = bA + i; if (q < E1CAP) { e1s[q] = ebS[i]; e1d[q] = ebD[i]; }
  }
}

// K4: per-edge GEMM layer 1 — row e: x[e1s[e]] @ w1 * w_e, atomic-add into agg1c[map1[e1d[e]]]
__global__ __launch_bounds__(256) void edgegemm1_kernel(const float* __restrict__ x,
    const float* __restrict__ w, const int* __restrict__ e1s,
    const int* __restrict__ e1d, const int* __restrict__ deg,
    const int* __restrict__ map1, float* __restrict__ agg1c,
    const int* __restrict__ cnt) {
  __shared__ float ws[F_IN * C];   // 32 KB
  __shared__ float xs[32 * F_IN];  // 16 KB
  __shared__ int qidx[32];
  __shared__ float wgt[32];
  int t = threadIdx.x;
  int n1 = cnt[I_E1]; if (n1 > E1CAP) n1 = E1CAP;
  int s1c = cnt[I_S1]; if (s1c > S1CAP) s1c = S1CAP;
  for (int i = t; i < F_IN * C; i += 256) ws[i] = w[i];
  int ntile = (n1 + 31) / 32;
  for (int tile = blockIdx.x; tile < ntile; tile += gridDim.x) {
    __syncthreads();
    int r0 = tile * 32;
    for (int i = t; i < 32 * F_IN; i += 256) {
      int r = r0 + (i >> 7);
      xs[i] = (r < n1) ? x[(size_t)e1s[r] * F_IN + (i & 127)] : 0.0f;
    }
    if (t < 32) {
      int r = r0 + t;
      if (r < n1) {
        int s = e1s[r], d = e1d[r];
        int q = map1[d];
        qidx[t] = ((unsigned)q < (unsigned)s1c) ? q : -1;
        wgt[t] = rsqrtf((float)deg[s] + 1.0f) * rsqrtf((float)deg[d] + 1.0f);
      } else qidx[t] = -1;
    }
    __syncthreads();
    int c = t & 63, rb = t >> 6;
    float acc[8];
#pragma unroll
    for (int j = 0; j < 8; ++j) acc[j] = 0.f;
    for (int k = 0; k < F_IN; ++k) {
      float wv = ws[k * C + c];
#pragma unroll
      for (int j = 0; j < 8; ++j)
        acc[j] += xs[(rb + j * 4) * F_IN + k] * wv;
    }
#pragma unroll
    for (int j = 0; j < 8; ++j) {
      int r = rb + j * 4;
      int q = qidx[r];
      if (q >= 0) atomicAdd(&agg1c[(size_t)q * C + c], acc[j] * wgt[r]);
    }
  }
}

// K5: xw2c = relu(agg1c + b1) @ w2  (self-term already in agg1c via pseudo-edges)
__global__ __launch_bounds__(256) void gemm2c_kernel(const float* __restrict__ agg1c,
    const float* __restrict__ b1, const float* __restrict__ w,
    float* __restrict__ xw2c, const int* __restrict__ cnt) {
  __shared__ float ws[C * C];   // 16 KB
  __shared__ float xs[64 * C];  // 16 KB
  int t = threadIdx.x;
  int sc = cnt[I_S1]; if (sc > S1CAP) sc = S1CAP;
  for (int i = t; i < C * C; i += 256) ws[i] = w[i];
  int ntile = (sc + 63) / 64;
  for (int tile = blockIdx.x; tile < ntile; tile += gridDim.x) {
    __syncthreads();
    int r0 = tile * 64;
    for (int i = t; i < 64 * C; i += 256) {
      int r = r0 + (i >> 6), cc = i & 63;
      xs[i] = (r < sc) ? fmaxf(agg1c[(size_t)r * C + cc] + b1[cc], 0.0f) : 0.0f;
    }
    __syncthreads();
    int c = t & 63, rb = t >> 6;
    float acc[16];
#pragma unroll
    for (int j = 0; j < 16; ++j) acc[j] = 0.f;
    for (int k = 0; k < C; ++k) {
      float wv = ws[k * C + c];
#pragma unroll
      for (int j = 0; j < 16; ++j)
        acc[j] += xs[(rb + j * 4) * C + k] * wv;
    }
#pragma unroll
    for (int j = 0; j < 16; ++j) {
      int r = r0 + rb + j * 4;
      if (r < sc) xw2c[(size_t)r * C + c] = acc[j];
    }
  }
}

// K6: gather2 — wide kernel, wave per E2 edge, atomic into global agg2c (pre-zeroed)
__global__ __launch_bounds__(256) void gather2_kernel(const int* __restrict__ e2s,
    const int* __restrict__ e2d, const int* __restrict__ deg,
    const int* __restrict__ map1, const float* __restrict__ xw2c,
    float* __restrict__ agg2c, const int* __restrict__ cnt) {
  int n2 = cnt[I_E2]; if (n2 > E2CAP) n2 = E2CAP;
  int gid = blockIdx.x * 256 + threadIdx.x;
  int i = gid >> 6, lane = gid & 63;
  int stride = (gridDim.x * 256) >> 6;
  for (; i < n2; i += stride) {
    int s = e2s[i], d = e2d[i];
    int q = map1[d];
    if ((unsigned)q < (unsigned)ELCAP) {
      float w = rsqrtf((float)deg[s] + 1.0f) * rsqrtf((float)deg[d] + 1.0f);
      atomicAdd(&agg2c[(size_t)q * C + lane], w * xw2c[(size_t)map1[s] * C + lane]);
    }
  }
}

// K7: single block — layer-2 self-term + rank-ordered sigmoid readout
__global__ __launch_bounds__(256) void readout_kernel(const int* __restrict__ src,
    const int* __restrict__ dst, const float* __restrict__ agg2c,
    const int* __restrict__ deg, const int* __restrict__ map1,
    const float* __restrict__ xw2c, const float* __restrict__ b2,
    const float* __restrict__ w_ro, const float* __restrict__ b_ro,
    const int* __restrict__ node_p, const int* __restrict__ elist,
    const int* __restrict__ cnt, int K, float* __restrict__ out) {
  __shared__ int ids[ELCAP];
  int t = threadIdx.x;
  int n = cnt[I_EL];
  if (n > K) n = K;
  if (n > ELCAP) n = ELCAP;
  for (int i = t; i < n; i += 256) ids[i] = elist[i];
  __syncthreads();
  int node = *node_p;
  for (int i = t; i < n; i += 256) {
    int eid = ids[i];
    int rank = 0;
    for (int j = 0; j < n; ++j) rank += (ids[j] < eid) ? 1 : 0;
    int s = src[eid], d = dst[eid];
    int tgt = (s == node) ? d : s;
    int q = map1[tgt];
    float dv = rsqrtf((float)deg[tgt] + 1.0f);
    float acc = 0.f;
    for (int c2 = 0; c2 < C; ++c2) {
      float h = agg2c[(size_t)q * C + c2] + xw2c[(size_t)q * C + c2] * dv * dv + b2[c2];
      acc += fmaxf(h, 0.f) * w_ro[c2];
    }
    acc += b_ro[0];
    out[rank] = 1.0f / (1.0f + expf(-acc));
    out[K + rank] = (float)tgt;
  }
}

extern "C" void kernel_launch(void* const* d_in, const int* in_sizes, int n_in,
                              void* d_out, int out_size, void* d_ws, size_t ws_size,
                              hipStream_t stream) {
  const float* x    = (const float*)d_in[0];
  const int*   ei   = (const int*)d_in[1];
  const int*   node = (const int*)d_in[3];
  const float* w1   = (const float*)d_in[5];
  const float* b1   = (const float*)d_in[6];
  const float* w2   = (const float*)d_in[7];
  const float* b2   = (const float*)d_in[8];
  const float* w_ro = (const float*)d_in[9];
  const float* b_ro = (const float*)d_in[10];
  float* out = (float*)d_out;

  int nE = in_sizes[1] / 2;
  int nN = in_sizes[0] / F_IN;
  const int* src = ei;
  const int* dst = ei + nE;
  int K = out_size / 2;

  // ws layout (4-byte units); [deg|tflag|mark1|cnt|agg1c|agg2c] contiguous -> ONE memset
  int* w = (int*)d_ws;
  int*   deg    = w;          w += nN;
  int*   tflag  = w;          w += nN;
  int*   mark1  = w;          w += nN;
  int*   cnt    = w;          w += 16;
  float* agg1c  = (float*)w;  w += (size_t)S1CAP * C;
  float* agg2c  = (float*)w;  w += (size_t)ELCAP * C;
  int*   map1   = w;          w += nN;
  int*   elist  = w;          w += ELCAP;
  int*   s1list = w;          w += S1CAP;
  int*   e2s    = w;          w += E2CAP;
  int*   e2d    = w;          w += E2CAP;
  int*   e1s    = w;          w += E1CAP;
  int*   e1d    = w;          w += E1CAP;
  float* xw2c   = (float*)w;  w += (size_t)S1CAP * C;

  hipMemsetAsync(deg, 0,
      ((size_t)3 * nN + 16 + (size_t)S1CAP * C + (size_t)ELCAP * C) * 4, stream);

  mask_hist_kernel<<<(nE + 255) / 256, 256, 0, stream>>>(src, dst, node, deg, tflag,
      mark1, map1, elist, s1list, e1s, e1d, cnt, nE);
  scanB_kernel<<<NSCAN, 256, 0, stream>>>(src, dst, tflag, mark1, map1, s1list,
      e2s, e2d, e1s, e1d, cnt, nE);
  scanC_kernel<<<NSCAN, 256, 0, stream>>>(src, dst, mark1, e1s, e1d, cnt, nE);
  edgegemm1_kernel<<<512, 256, 0, stream>>>(x, w1, e1s, e1d, deg, map1, agg1c, cnt);
  gemm2c_kernel<<<16, 256, 0, stream>>>(agg1c, b1, w2, xw2c, cnt);
  gather2_kernel<<<64, 256, 0, stream>>>(e2s, e2d, deg, map1, xw2c, agg2c, cnt);
  readout_kernel<<<1, 256, 0, stream>>>(src, dst, agg2c, deg, map1, xw2c, b2,
                                        w_ro, b_ro, node, elist, cnt, K, out);
}